// Round 4
// baseline (266.805 us; speedup 1.0000x reference)
//
#include <hip/hip_runtime.h>
#include <hip/hip_bf16.h>

#define NH 16
#define HD 64
#define EMB 1024
#define BB 4
#define TT 2048
#define MTOT (BB*TT)        // 8192 rows
#define N1 (3*NH*HD)        // 3072
#define KD EMB              // 1024

// q scale: (1/sqrt(HD)) * log2(e) — softmax computed in exp2 domain
#define QSCALE 0.18033688011112042f
// fixed softmax "max" in exp2 domain (exact after 1/l normalization)
#define FMAX 14.0f

typedef __bf16 bf16x8 __attribute__((ext_vector_type(8)));
typedef __bf16 bf16x4 __attribute__((ext_vector_type(4)));
typedef float  f32x4  __attribute__((ext_vector_type(4)));
typedef __hip_bfloat16 hbf;

__device__ __forceinline__ void async_copy16(const hbf* g, hbf* l) {
    __builtin_amdgcn_global_load_lds(
        (const __attribute__((address_space(1))) void*)g,
        (__attribute__((address_space(3))) void*)l, 16, 0, 0);
}

__device__ __forceinline__ bf16x4 pack4(float x0, float x1, float x2, float x3) {
    union { bf16x4 v; hbf a[4]; } u;
    u.a[0] = __float2bfloat16(x0);
    u.a[1] = __float2bfloat16(x1);
    u.a[2] = __float2bfloat16(x2);
    u.a[3] = __float2bfloat16(x3);
    return u.v;
}

// ---------------- conversion kernels ----------------

__global__ __launch_bounds__(256) void f32_to_bf16_v4(const float* __restrict__ in,
                                                      hbf* __restrict__ out, int n4) {
    int i = blockIdx.x * blockDim.x + threadIdx.x;
    if (i < n4) {
        float4 v = ((const float4*)in)[i];
        *(bf16x4*)(out + 4 * (size_t)i) = pack4(v.x, v.y, v.z, v.w);
    }
}

// LDS-tiled transposing convert: out[c*R + r] = bf16(in[r*C + c]); R,C % 64 == 0
__global__ __launch_bounds__(256) void f32_to_bf16_T(const float* __restrict__ in,
                                                     hbf* __restrict__ out, int R, int C) {
    __shared__ float T[64][65];
    int bc = blockIdx.x % (C / 64), br = blockIdx.x / (C / 64);
    int r0 = br * 64, c0 = bc * 64;
    int tr = threadIdx.x >> 6, tc = threadIdx.x & 63;
    #pragma unroll
    for (int i = 0; i < 16; ++i)
        T[4 * i + tr][tc] = in[(size_t)(r0 + 4 * i + tr) * C + c0 + tc];
    __syncthreads();
    #pragma unroll
    for (int i = 0; i < 16; ++i)
        out[(size_t)(c0 + 4 * i + tr) * R + r0 + tc] = __float2bfloat16(T[tc][4 * i + tr]);
}

// ---------------- GEMM v2: 64x64 wave tiles, BK=32, lead-2 counted-vmcnt pipeline ----
// 256 thr = 4 waves (2x2), block 128x128, LDS 32KB dbuf -> 4 blocks/CU.
// 8 ds_read_b128 per 16 MFMA (0.5 reads/MFMA). Stage t+2 into just-freed buffer
// behind lgkmcnt(0)+barrier; one counted vmcnt(4) per tile (never 0 in-loop).
// XOR swizzle: slot = chunk ^ (row&3) both at stage-source and frag-read.
// MODE 0: qkv scatter epilogue. MODE 1: f32 + bias.

template<int NBN, int MODE>
__global__ __launch_bounds__(256, 4) void gemm_v2(
    const hbf* __restrict__ A, const hbf* __restrict__ Bt,
    hbf* __restrict__ qh, hbf* __restrict__ kh, hbf* __restrict__ vt,
    const float* __restrict__ bias, float* __restrict__ out)
{
    constexpr int NKT = KD / 32;                 // 32 K-tiles
    __shared__ __align__(16) hbf As[2 * 128 * 32];   // 16 KB
    __shared__ __align__(16) hbf Bs[2 * 128 * 32];   // 16 KB

    int tid = threadIdx.x;
    int wv = tid >> 6, lane = tid & 63;
    int g = lane >> 4, c = lane & 15;
    int wm = wv >> 1, wn = wv & 1;               // 2x2 waves; wave out = 64x64
    // bijective XCD swizzle (grid % 8 == 0): consecutive wg share an XCD
    int wg = (blockIdx.x & 7) * (8 * NBN) + (blockIdx.x >> 3);
    int bn = wg % NBN, bm = wg / NBN;
    int m0 = bm * 128, n0 = bn * 128;

    // staging: 512 chunks of 16B per 128x32 tile; thread does chunks tid, 256+tid
    int sr = tid >> 2;                           // row within 64-row half
    int sgc = (tid & 3) ^ (sr & 3);              // inverse-swizzled global chunk
    const hbf* Asrc0 = A  + (size_t)(m0 + sr) * KD + sgc * 8;
    const hbf* Asrc1 = A  + (size_t)(m0 + 64 + sr) * KD + sgc * 8;
    const hbf* Bsrc0 = Bt + (size_t)(n0 + sr) * KD + sgc * 8;
    const hbf* Bsrc1 = Bt + (size_t)(n0 + 64 + sr) * KD + sgc * 8;
    int ld0 = (tid & ~63) * 8, ld1 = 2048 + (tid & ~63) * 8;

#define STG(tt, buf) { \
    async_copy16(Asrc0 + (tt) * 32, As + (buf) * 4096 + ld0); \
    async_copy16(Asrc1 + (tt) * 32, As + (buf) * 4096 + ld1); \
    async_copy16(Bsrc0 + (tt) * 32, Bs + (buf) * 4096 + ld0); \
    async_copy16(Bsrc1 + (tt) * 32, Bs + (buf) * 4096 + ld1); }

    // fragment read offsets (swizzled): row&3 == c&3 (row base multiple of 4)
    int x3 = c & 3;
    int ao = (wm * 64 + c) * 32 + ((g ^ x3) << 3);
    int bo = (wn * 64 + c) * 32 + ((g ^ x3) << 3);

    f32x4 acc[4][4];
    #pragma unroll
    for (int i = 0; i < 4; ++i)
        #pragma unroll
        for (int j = 0; j < 4; ++j) acc[i][j] = (f32x4){0.f, 0.f, 0.f, 0.f};

    STG(0, 0);
    STG(1, 1);
    asm volatile("s_waitcnt vmcnt(4)" ::: "memory");   // tile0 landed; tile1 in flight
    asm volatile("s_barrier" ::: "memory");
    __builtin_amdgcn_sched_barrier(0);

    for (int t = 0; t < NKT; ++t) {
        int cur = t & 1;
        const hbf* Ab = As + cur * 4096;
        const hbf* Bb = Bs + cur * 4096;
        bf16x8 af[4], bfr[4];
        #pragma unroll
        for (int i = 0; i < 4; ++i) af[i] = *(const bf16x8*)(Ab + ao + i * 512);
        #pragma unroll
        for (int j = 0; j < 4; ++j) bfr[j] = *(const bf16x8*)(Bb + bo + j * 512);
        asm volatile("s_waitcnt lgkmcnt(0)" ::: "memory");  // reads done -> WAR-safe
        __builtin_amdgcn_sched_barrier(0);
        asm volatile("s_barrier" ::: "memory");             // all waves done with buf[cur]
        __builtin_amdgcn_sched_barrier(0);
        if (t + 2 < NKT) STG(t + 2, cur);                   // refill freed buffer
        __builtin_amdgcn_s_setprio(1);
        #pragma unroll
        for (int i = 0; i < 4; ++i)
            #pragma unroll
            for (int j = 0; j < 4; ++j)
                acc[i][j] = __builtin_amdgcn_mfma_f32_16x16x32_bf16(af[i], bfr[j], acc[i][j], 0, 0, 0);
        __builtin_amdgcn_s_setprio(0);
        if (t + 2 < NKT) { asm volatile("s_waitcnt vmcnt(4)" ::: "memory"); }
        else             { asm volatile("s_waitcnt vmcnt(0)" ::: "memory"); }
        asm volatile("s_barrier" ::: "memory");             // tile t+1 ready for all
        __builtin_amdgcn_sched_barrier(0);
    }
#undef STG

    if constexpr (MODE == 0) {
        int colbase = n0 + wn * 64;                  // one full head per wave
        int which = colbase >> 10;                   // 0:q 1:k 2:v
        int h = (colbase & 1023) >> 6;
        int b = m0 / TT;
        int trow = (m0 % TT) + wm * 64;
        if (which < 2) {
            float scale = (which == 0) ? QSCALE : 1.0f;
            hbf* dst = ((which == 0) ? qh : kh) + ((size_t)b * NH + h) * TT * HD;
            #pragma unroll
            for (int i = 0; i < 4; ++i)
                #pragma unroll
                for (int j = 0; j < 4; ++j) {
                    int d = j * 16 + c;
                    #pragma unroll
                    for (int r = 0; r < 4; ++r) {
                        int trw = trow + i * 16 + g * 4 + r;
                        dst[(size_t)trw * HD + d] = __float2bfloat16(acc[i][j][r] * scale);
                    }
                }
        } else {
            hbf* dst = vt + ((size_t)b * NH + h) * TT * HD;   // [HD][TT] per head
            #pragma unroll
            for (int i = 0; i < 4; ++i)
                #pragma unroll
                for (int j = 0; j < 4; ++j) {
                    int d = j * 16 + c;
                    #pragma unroll
                    for (int r = 0; r < 4; ++r) {
                        int trw = trow + i * 16 + g * 4 + r;
                        dst[(size_t)d * TT + trw] = __float2bfloat16(acc[i][j][r]);
                    }
                }
        }
    } else {
        #pragma unroll
        for (int i = 0; i < 4; ++i)
            #pragma unroll
            for (int j = 0; j < 4; ++j) {
                int col = n0 + wn * 64 + j * 16 + c;
                float bv = bias[col];
                #pragma unroll
                for (int r = 0; r < 4; ++r) {
                    int row = m0 + wm * 64 + i * 16 + g * 4 + r;
                    out[(size_t)row * EMB + col] = acc[i][j][r] + bv;
                }
            }
    }
}

// ---------------- flash attention v6b: dbuf 64-key tiles, counted vmcnt ----------------
// (v6 + fix: K-tile stage advance is tt*64*HD — K is [TT][HD]; V stays tt*64, [HD][TT].)
// 1024 blocks: one 128-q supertile each (big-sst dispatched first; XCD-major bh).
// LDS 48KB (Ks/Vs dbuf 16KB each + Ps 16KB) -> 3 blocks/CU.
// Per tile: compute -> barrier -> stage(t+2) into freed buffer -> vmcnt(2) -> barrier.
// Fixed-max softmax in exp2 domain (exact after 1/l); l via ones-MFMA.

__global__ __launch_bounds__(512, 6) void attn(
    const hbf* __restrict__ qh, const hbf* __restrict__ kh, const hbf* __restrict__ vt,
    hbf* __restrict__ y)
{
    __shared__ __align__(16) hbf Ks[2 * 64 * 64];   // 16 KB [key][dim-swz] dbuf
    __shared__ __align__(16) hbf Vs[2 * 64 * 64];   // 16 KB [dim][key-swz] dbuf
    __shared__ __align__(16) hbf Ps[8][16 * 64];    // 16 KB per-wave P^T

    int tid = threadIdx.x;
    int wv = tid >> 6, lane = tid & 63;
    int g = lane >> 4, c = lane & 15;
    int c7 = c & 7;

    int bidx = blockIdx.x;
    int bh = (bidx & 7) | (((bidx >> 7) & 7) << 3);   // XCD-major bh
    int sst = 15 - ((bidx >> 3) & 15);                // big supertiles first
    int b = bh >> 4, h = bh & 15;
    int qb = sst * 128;
    int q0 = qb + wv * 16;
    int kend = q0 + 16;
    int nt = 2 * sst + 2;                             // 64-key tiles to process

    const hbf* Q = qh + (size_t)bh * TT * HD;
    const hbf* K = kh + (size_t)bh * TT * HD;
    const hbf* V = vt + (size_t)bh * TT * HD;   // [HD][TT]
    hbf* Pq = &Ps[wv][0];

    // staging: 512 chunks of 16B per 64x64 tile; 1 K-chunk + 1 V-chunk per thread
    int skey = tid >> 3, schunk = tid & 7;
    int sswz = (schunk ^ (skey & 7)) * 8;
    const hbf* Ksrc = K + (size_t)skey * HD + sswz;   // + tt*64*HD
    const hbf* Vsrc = V + (size_t)skey * TT + sswz;   // dim=skey; + tt*64
    int sdst = (tid & ~63) * 8;

#define ASTG(tt, buf) { \
    async_copy16(Ksrc + (size_t)(tt) * 64 * HD, Ks + (buf) * 4096 + sdst); \
    async_copy16(Vsrc + (tt) * 64, Vs + (buf) * 4096 + sdst); }

    bf16x8 aq0 = *(const bf16x8*)(Q + (size_t)(q0 + c) * HD + g * 8);
    bf16x8 aq1 = *(const bf16x8*)(Q + (size_t)(q0 + c) * HD + 32 + g * 8);

    union { bf16x8 v; hbf a[8]; } uo;
    #pragma unroll
    for (int i = 0; i < 8; ++i) uo.a[i] = __float2bfloat16(1.0f);
    const bf16x8 ones8 = uo.v;

    f32x4 lacc = (f32x4){0.f, 0.f, 0.f, 0.f};
    f32x4 o[4];
    #pragma unroll
    for (int d = 0; d < 4; ++d) o[d] = (f32x4){0.f, 0.f, 0.f, 0.f};

    ASTG(0, 0);
    ASTG(1, 1);
    asm volatile("s_waitcnt vmcnt(2)" ::: "memory");   // tile0 landed; tile1 in flight
    asm volatile("s_barrier" ::: "memory");
    __builtin_amdgcn_sched_barrier(0);

    for (int tt = 0; tt < nt; ++tt) {
        int cur = tt & 1;
        int k0 = tt * 64;
        const hbf* Kb = Ks + cur * 4096;
        const hbf* Vb = Vs + cur * 4096;
        if (k0 < kend) {                              // wave-uniform
            // ---- S^T = K·Q^T - FMAX, 4 subtiles of 16 keys ----
            f32x4 s[4];
            #pragma unroll
            for (int t4 = 0; t4 < 4; ++t4) {
                int kt = k0 + 16 * t4;
                if (kt < kend) {                      // wave-uniform
                    int rb = (16 * t4 + c) * 64;
                    bf16x8 kf0 = *(const bf16x8*)(Kb + rb + ((g ^ c7) << 3));
                    bf16x8 kf1 = *(const bf16x8*)(Kb + rb + (((4 + g) ^ c7) << 3));
                    f32x4 a = (f32x4){-FMAX, -FMAX, -FMAX, -FMAX};
                    a = __builtin_amdgcn_mfma_f32_16x16x32_bf16(kf0, aq0, a, 0, 0, 0);
                    a = __builtin_amdgcn_mfma_f32_16x16x32_bf16(kf1, aq1, a, 0, 0, 0);
                    if (kt == q0) {                   // diagonal: key<=q ⇔ g*4+r<=c
                        #pragma unroll
                        for (int r = 0; r < 4; ++r)
                            a[r] = (g * 4 + r <= c) ? a[r] : -1e30f;
                    }
                    s[t4] = a;
                } else
                    s[t4] = (f32x4){-1e30f, -1e30f, -1e30f, -1e30f};
            }
            // ---- P = exp2(S - FMAX) straight to LDS ----
            #pragma unroll
            for (int t4 = 0; t4 < 4; ++t4) {
                f32x4 e;
                #pragma unroll
                for (int r = 0; r < 4; ++r) e[r] = __builtin_amdgcn_exp2f(s[t4][r]);
                *(bf16x4*)(Pq + c * 64 + (((2 * t4 + (g >> 1)) ^ c7) << 3) + ((g & 1) << 2)) =
                    pack4(e[0], e[1], e[2], e[3]);
            }
            // ---- O^T += V^T·P^T ; l via ones·P^T ----
            #pragma unroll
            for (int sc = 0; sc < 2; ++sc) {
                if (k0 + 32 * sc < kend) {            // wave-uniform
                    bf16x8 pf = *(const bf16x8*)(Pq + c * 64 + (((4 * sc + g) ^ c7) << 3));
                    lacc = __builtin_amdgcn_mfma_f32_16x16x32_bf16(ones8, pf, lacc, 0, 0, 0);
                    #pragma unroll
                    for (int d = 0; d < 4; ++d) {
                        bf16x8 vf = *(const bf16x8*)(Vb + (d * 16 + c) * 64 +
                                      (((4 * sc + g) ^ c7) << 3));
                        o[d] = __builtin_amdgcn_mfma_f32_16x16x32_bf16(vf, pf, o[d], 0, 0, 0);
                    }
                }
            }
        }
        asm volatile("s_barrier" ::: "memory");       // all waves done with buf[cur]
        __builtin_amdgcn_sched_barrier(0);
        if (tt + 2 < nt) ASTG(tt + 2, cur);           // refill freed buffer
        if (tt + 2 < nt) { asm volatile("s_waitcnt vmcnt(2)" ::: "memory"); }
        else             { asm volatile("s_waitcnt vmcnt(0)" ::: "memory"); }
        asm volatile("s_barrier" ::: "memory");       // tile tt+1 ready for all
        __builtin_amdgcn_sched_barrier(0);
    }
#undef ASTG

    float inv = 1.0f / lacc[0];
    #pragma unroll
    for (int d = 0; d < 4; ++d) {
        *(bf16x4*)(y + (size_t)(b * TT + q0 + c) * EMB + h * HD + d * 16 + g * 4) =
            pack4(o[d][0] * inv, o[d][1] * inv, o[d][2] * inv, o[d][3] * inv);
    }
}

// ---------------- launch ----------------

extern "C" void kernel_launch(void* const* d_in, const int* in_sizes, int n_in,
                              void* d_out, int out_size, void* d_ws, size_t ws_size,
                              hipStream_t stream)
{
    const float* x      = (const float*)d_in[0];
    const float* W_attn = (const float*)d_in[1];
    const float* W_proj = (const float*)d_in[2];
    const float* b_proj = (const float*)d_in[3];
    float* out = (float*)d_out;

    char* ws = (char*)d_ws;
    hbf* xb    = (hbf*)ws; ws += (size_t)MTOT * KD * 2;
    hbf* wab_t = (hbf*)ws; ws += (size_t)N1 * KD * 2;
    hbf* wpb_t = (hbf*)ws; ws += (size_t)EMB * EMB * 2;
    hbf* qh    = (hbf*)ws; ws += (size_t)MTOT * EMB * 2;
    hbf* kh    = (hbf*)ws; ws += (size_t)MTOT * EMB * 2;
    hbf* vt    = (hbf*)ws; ws += (size_t)MTOT * EMB * 2;
    hbf* yb    = (hbf*)ws; ws += (size_t)MTOT * EMB * 2;

    f32_to_bf16_v4<<<(MTOT * KD / 4 + 255) / 256, 256, 0, stream>>>(x, xb, MTOT * KD / 4);
    f32_to_bf16_T<<<(KD / 64) * (N1 / 64), 256, 0, stream>>>(W_attn, wab_t, KD, N1);
    f32_to_bf16_T<<<(KD / 64) * (EMB / 64), 256, 0, stream>>>(W_proj, wpb_t, KD, EMB);

    gemm_v2<N1 / 128, 0><<<(MTOT / 128) * (N1 / 128), 256, 0, stream>>>(
        xb, wab_t, qh, kh, vt, nullptr, nullptr);
    attn<<<BB * NH * 16, 512, 0, stream>>>(qh, kh, vt, yb);
    gemm_v2<EMB / 128, 1><<<(MTOT / 128) * (EMB / 128), 256, 0, stream>>>(
        yb, wpb_t, nullptr, nullptr, nullptr, b_proj, out);
}